// Round 1
// baseline (464.825 us; speedup 1.0000x reference)
//
#include <hip/hip_runtime.h>
#include <stdint.h>

static constexpr int N = 2048;
static constexpr int B = 2;
static constexpr int T = 3;
static constexpr int H = 4;
static constexpr int D = 16;
static constexpr float NEG = -1e30f;

// ---- pack graph!=0 into bits: mask64[i*32 + j/64] ----
__global__ void pack_mask(const float* __restrict__ g, unsigned long long* __restrict__ mb) {
    int idx = blockIdx.x * 256 + threadIdx.x;            // over N*N
    float v = g[idx];
    unsigned long long bal = __ballot(v != 0.0f);
    if ((threadIdx.x & 63) == 0) mb[idx >> 6] = bal;
}

// ---- h1[t][b][h][n][d] = sum_c flow_x[b][n][t][c] * W1[t][h][c][d] ----
__global__ void k_h1(const float* __restrict__ fx, const float* __restrict__ W1,
                     float* __restrict__ h1) {
    int id = blockIdx.x * 256 + threadIdx.x;             // T*B*H*N threads
    int n = id & (N - 1);
    int head = id >> 11;                                 // (t*B+b)*H+h
    int t = head >> 3;
    int b = (head >> 2) & 1;
    int h = head & 3;
    const float* f = fx + (((size_t)(b * N + n)) * T + t) * D;
    const float* w = W1 + ((t * H + h) * D) * (size_t)D;
    float fr[D];
    const float4* f4 = (const float4*)f;
#pragma unroll
    for (int k = 0; k < 4; ++k) {
        float4 v = f4[k];
        fr[4*k] = v.x; fr[4*k+1] = v.y; fr[4*k+2] = v.z; fr[4*k+3] = v.w;
    }
    float acc[D] = {};
#pragma unroll
    for (int c = 0; c < D; ++c)
#pragma unroll
        for (int d = 0; d < D; ++d) acc[d] = fmaf(fr[c], w[c*D+d], acc[d]);
    float* o = h1 + (size_t)id * D;
#pragma unroll
    for (int d = 0; d < D; ++d) o[d] = acc[d];
}

// ---- y[r][0..15] = x[r][0..KIN-1] @ W[(r>>SHIFT)][KIN][16] ----
template<int KIN, int SHIFT>
__global__ void k_rowmm(const float* __restrict__ x, const float* __restrict__ Wbase,
                        float* __restrict__ y) {
    int id = blockIdx.x * 256 + threadIdx.x;
    const float* __restrict__ xr = x + (size_t)id * KIN;
    const float* __restrict__ w = Wbase + (size_t)(id >> SHIFT) * KIN * D;
    float acc[D] = {};
#pragma unroll
    for (int c4 = 0; c4 < KIN/4; ++c4) {
        float4 xv = ((const float4*)xr)[c4];
        float xs[4] = {xv.x, xv.y, xv.z, xv.w};
#pragma unroll
        for (int q = 0; q < 4; ++q) {
            int c = c4*4 + q;
#pragma unroll
            for (int d = 0; d < D; ++d) acc[d] = fmaf(xs[q], w[c*D+d], acc[d]);
        }
    }
    float* o = y + (size_t)id * D;
#pragma unroll
    for (int d = 0; d < D; ++d) o[d] = acc[d];
}

// ---- fused masked-softmax attention over one head; online softmax,
//      j-range split across SPLIT waves, LDS merge ----
template<int LAYER, int SPLIT, bool LEAKY>
__global__ __launch_bounds__(64*SPLIT) void attn(
        const float* __restrict__ hsrc, const uint32_t* __restrict__ mask,
        const float* __restrict__ bias, float* __restrict__ out) {
    constexpr int JLEN = N / SPLIT;
    const int lane = threadIdx.x & 63;
    const int wv = threadIdx.x >> 6;
    const int row = blockIdx.x * 64 + lane;
    const int head = blockIdx.y;

    const float* __restrict__ hh = hsrc + (size_t)head * N * D;
    const float* bb; float* op; int ostride;
    if constexpr (LAYER == 1) {
        int t = head >> 3, b = (head >> 2) & 1, hd = head & 3;
        bb = bias + (t * H + hd) * D;
        op = out + ((size_t)(t * B + b) * N) * (H * D) + hd * D;
        ostride = H * D;                 // x2[t][b][n][64]
    } else if constexpr (LAYER == 2) {
        int t = head >> 1, b = head & 1;
        bb = bias + t * D;
        op = out + (size_t)b * N * (T * D) + t * D;
        ostride = T * D;                 // hidden[b][n][48]
    } else {
        bb = bias;
        op = out + (size_t)head * N * D;
        ostride = D;                     // out[b][n][16]
    }

    float hi[D];
    {
        const float4* r4 = (const float4*)(hh + (size_t)row * D);
#pragma unroll
        for (int k = 0; k < 4; ++k) {
            float4 v = r4[k];
            hi[4*k] = v.x; hi[4*k+1] = v.y; hi[4*k+2] = v.z; hi[4*k+3] = v.w;
        }
    }

    const int j0 = __builtin_amdgcn_readfirstlane(wv * JLEN);
    const uint32_t* __restrict__ mrow = mask + (size_t)row * (N/32) + (j0 >> 5);
    float m = NEG, l = 0.f;
    float o[D] = {};

    for (int w = 0; w < JLEN/32; ++w) {
        uint32_t mw = mrow[w];
        int jb = j0 + w*32;
#pragma unroll 4
        for (int u = 0; u < 32; ++u) {
            const float4* h4 = (const float4*)(hh + (size_t)(jb + u) * D);
            float4 v0 = h4[0], v1 = h4[1], v2 = h4[2], v3 = h4[3];
            float hj[D];
            hj[0]=v0.x; hj[1]=v0.y; hj[2]=v0.z; hj[3]=v0.w;
            hj[4]=v1.x; hj[5]=v1.y; hj[6]=v1.z; hj[7]=v1.w;
            hj[8]=v2.x; hj[9]=v2.y; hj[10]=v2.z; hj[11]=v2.w;
            hj[12]=v3.x; hj[13]=v3.y; hj[14]=v3.z; hj[15]=v3.w;
            float s0=0.f, s1=0.f, s2=0.f, s3=0.f;
#pragma unroll
            for (int k = 0; k < 4; ++k) {
                s0 = fmaf(hi[k],    hj[k],    s0);
                s1 = fmaf(hi[k+4],  hj[k+4],  s1);
                s2 = fmaf(hi[k+8],  hj[k+8],  s2);
                s3 = fmaf(hi[k+12], hj[k+12], s3);
            }
            float s = (s0 + s1) + (s2 + s3);
            float se = ((mw >> u) & 1u) ? s : NEG;
            if (se > m) {                      // rare after warmup
                float cc = __expf(m - se);     // zeroes any masked-prefix garbage
                l *= cc;
#pragma unroll
                for (int k = 0; k < D; ++k) o[k] *= cc;
                m = se;
            }
            float wg = __expf(se - m);         // masked: exp(-1e30-m)=0 (or 1 pre-warmup, later zeroed)
            l += wg;
#pragma unroll
            for (int k = 0; k < D; ++k) o[k] = fmaf(wg, hj[k], o[k]);
        }
    }

    __shared__ float sm[SPLIT][64];
    __shared__ float sl[SPLIT][64];
    __shared__ float so[SPLIT][64][D+1];   // +1 pad: conflict-free column reads in merge
    sm[wv][lane] = m;
    sl[wv][lane] = l;
#pragma unroll
    for (int k = 0; k < D; ++k) so[wv][lane][k] = o[k];
    __syncthreads();

    if (threadIdx.x < 64) {
        int r = threadIdx.x;
        float M = sm[0][r];
#pragma unroll
        for (int s = 1; s < SPLIT; ++s) M = fmaxf(M, sm[s][r]);
        float L = 0.f, O[D] = {};
#pragma unroll
        for (int s = 0; s < SPLIT; ++s) {
            float cc = __expf(sm[s][r] - M);
            L = fmaf(cc, sl[s][r], L);
#pragma unroll
            for (int k = 0; k < D; ++k) O[k] = fmaf(cc, so[s][r][k], O[k]);
        }
        float inv = 1.0f / L;                 // L >= 1 always (max split has c=1, l>=1)
        int rr = blockIdx.x * 64 + r;
        float* orow = op + (size_t)rr * ostride;
#pragma unroll
        for (int k = 0; k < D; ++k) {
            float v = fmaf(O[k], inv, bb[k]);
            if (LEAKY) v = (v > 0.f) ? v : 0.01f * v;
            orow[k] = v;
        }
    }
}

extern "C" void kernel_launch(void* const* d_in, const int* in_sizes, int n_in,
                              void* d_out, int out_size, void* d_ws, size_t ws_size,
                              hipStream_t stream) {
    const float* fx    = (const float*)d_in[0];
    const float* graph = (const float*)d_in[1];
    const float* W1    = (const float*)d_in[2];
    const float* b1    = (const float*)d_in[3];
    const float* W2    = (const float*)d_in[4];
    const float* b2    = (const float*)d_in[5];
    const float* W3    = (const float*)d_in[6];
    const float* b3    = (const float*)d_in[7];
    float* out = (float*)d_out;

    char* ws = (char*)d_ws;
    unsigned long long* mask64 = (unsigned long long*)ws;            // N*N/8 = 512 KB
    float* h1     = (float*)(ws + (size_t)(N*(size_t)N/8));          // [24][N][16]
    float* x2     = h1 + (size_t)T*B*H*N*D;                          // [T][B][N][64]
    float* h2     = x2 + (size_t)T*B*N*H*D;                          // [T][B][N][16]
    float* hidden = h2 + (size_t)T*B*N*D;                            // [B][N][48]
    float* h3     = hidden + (size_t)B*N*T*D;                        // [B][N][16]

    pack_mask<<<N*N/256, 256, 0, stream>>>(graph, mask64);
    k_h1<<<T*B*H*N/256, 256, 0, stream>>>(fx, W1, h1);
    attn<1,4,true><<<dim3(N/64, T*B*H), 256, 0, stream>>>(h1, (const uint32_t*)mask64, b1, x2);
    k_rowmm<H*D,12><<<T*B*N/256, 256, 0, stream>>>(x2, W2, h2);      // t = id>>12 (B*N=4096)
    attn<2,8,true><<<dim3(N/64, T*B), 512, 0, stream>>>(h2, (const uint32_t*)mask64, b2, hidden);
    k_rowmm<T*D,20><<<B*N/256, 256, 0, stream>>>(hidden, W3, h3);    // single W3
    attn<3,8,false><<<dim3(N/64, B), 512, 0, stream>>>(h3, (const uint32_t*)mask64, b3, out);
}

// Round 2
// 306.955 us; speedup vs baseline: 1.5143x; 1.5143x over previous
//
#include <hip/hip_runtime.h>
#include <stdint.h>

static constexpr int N = 2048;
static constexpr int B = 2;
static constexpr int T = 3;
static constexpr int H = 4;
static constexpr int D = 16;
static constexpr float NEG = -1e30f;

// ---- pack graph!=0 into bits: mask64[i*32 + j/64] ----
__global__ void pack_mask(const float* __restrict__ g, unsigned long long* __restrict__ mb) {
    int idx = blockIdx.x * 256 + threadIdx.x;            // over N*N
    float v = g[idx];
    unsigned long long bal = __ballot(v != 0.0f);
    if ((threadIdx.x & 63) == 0) mb[idx >> 6] = bal;
}

// ---- h1[t][b][h][n][d] = sum_c flow_x[b][n][t][c] * W1[t][h][c][d] ----
__global__ void k_h1(const float* __restrict__ fx, const float* __restrict__ W1,
                     float* __restrict__ h1) {
    int id = blockIdx.x * 256 + threadIdx.x;             // T*B*H*N threads
    int n = id & (N - 1);
    int head = id >> 11;                                 // (t*B+b)*H+h
    int t = head >> 3;
    int b = (head >> 2) & 1;
    int h = head & 3;
    const float* f = fx + (((size_t)(b * N + n)) * T + t) * D;
    const float* w = W1 + ((t * H + h) * D) * (size_t)D;
    float fr[D];
    const float4* f4 = (const float4*)f;
#pragma unroll
    for (int k = 0; k < 4; ++k) {
        float4 v = f4[k];
        fr[4*k] = v.x; fr[4*k+1] = v.y; fr[4*k+2] = v.z; fr[4*k+3] = v.w;
    }
    float acc[D] = {};
#pragma unroll
    for (int c = 0; c < D; ++c)
#pragma unroll
        for (int d = 0; d < D; ++d) acc[d] = fmaf(fr[c], w[c*D+d], acc[d]);
    float* o = h1 + (size_t)id * D;
#pragma unroll
    for (int d = 0; d < D; ++d) o[d] = acc[d];
}

// ---- y[r][0..15] = x[r][0..KIN-1] @ W[(r>>SHIFT)][KIN][16] ----
template<int KIN, int SHIFT>
__global__ void k_rowmm(const float* __restrict__ x, const float* __restrict__ Wbase,
                        float* __restrict__ y) {
    int id = blockIdx.x * 256 + threadIdx.x;
    const float* __restrict__ xr = x + (size_t)id * KIN;
    const float* __restrict__ w = Wbase + (size_t)(id >> SHIFT) * KIN * D;
    float acc[D] = {};
#pragma unroll
    for (int c4 = 0; c4 < KIN/4; ++c4) {
        float4 xv = ((const float4*)xr)[c4];
        float xs[4] = {xv.x, xv.y, xv.z, xv.w};
#pragma unroll
        for (int q = 0; q < 4; ++q) {
            int c = c4*4 + q;
#pragma unroll
            for (int d = 0; d < D; ++d) acc[d] = fmaf(xs[q], w[c*D+d], acc[d]);
        }
    }
    float* o = y + (size_t)id * D;
#pragma unroll
    for (int d = 0; d < D; ++d) o[d] = acc[d];
}

// ================= shared inner loop (online softmax over a j-slice) =========
template<int SPLIT>
__device__ __forceinline__ void attn_slice(
        const float* __restrict__ hh, const uint32_t* __restrict__ mrow,
        const float (&hi)[D], int j0, int jlen,
        float& m, float& l, float (&o)[D]) {
    for (int w = 0; w < jlen/32; ++w) {
        uint32_t mw = mrow[w];
        int jb = j0 + w*32;
#pragma unroll 4
        for (int u = 0; u < 32; ++u) {
            const float4* h4 = (const float4*)(hh + (size_t)(jb + u) * D);
            float4 v0 = h4[0], v1 = h4[1], v2 = h4[2], v3 = h4[3];
            float hj[D];
            hj[0]=v0.x; hj[1]=v0.y; hj[2]=v0.z; hj[3]=v0.w;
            hj[4]=v1.x; hj[5]=v1.y; hj[6]=v1.z; hj[7]=v1.w;
            hj[8]=v2.x; hj[9]=v2.y; hj[10]=v2.z; hj[11]=v2.w;
            hj[12]=v3.x; hj[13]=v3.y; hj[14]=v3.z; hj[15]=v3.w;
            float s0=0.f, s1=0.f, s2=0.f, s3=0.f;
#pragma unroll
            for (int k = 0; k < 4; ++k) {
                s0 = fmaf(hi[k],    hj[k],    s0);
                s1 = fmaf(hi[k+4],  hj[k+4],  s1);
                s2 = fmaf(hi[k+8],  hj[k+8],  s2);
                s3 = fmaf(hi[k+12], hj[k+12], s3);
            }
            float s = (s0 + s1) + (s2 + s3);
            float se = ((mw >> u) & 1u) ? s : NEG;
            if (se > m) {                      // rare after warmup
                float cc = __expf(m - se);     // zeroes any masked-prefix garbage
                l *= cc;
#pragma unroll
                for (int k = 0; k < D; ++k) o[k] *= cc;
                m = se;
            }
            float wg = __expf(se - m);         // masked: 0 once m finite
            l += wg;
#pragma unroll
            for (int k = 0; k < D; ++k) o[k] = fmaf(wg, hj[k], o[k]);
        }
    }
}

// LDS merge of SPLIT wave-partials -> lane r (threadIdx.x<64) returns (M,L,O)
template<int SPLIT>
__device__ __forceinline__ bool block_merge(
        int lane, int wv, float m, float l, const float (&o)[D],
        float& M, float& L, float (&O)[D]) {
    __shared__ float sm[SPLIT][64];
    __shared__ float sl[SPLIT][64];
    __shared__ float so[SPLIT][64][D+1];
    sm[wv][lane] = m;
    sl[wv][lane] = l;
#pragma unroll
    for (int k = 0; k < D; ++k) so[wv][lane][k] = o[k];
    __syncthreads();
    if (threadIdx.x >= 64) return false;
    int r = threadIdx.x;
    M = sm[0][r];
#pragma unroll
    for (int s = 1; s < SPLIT; ++s) M = fmaxf(M, sm[s][r]);
    L = 0.f;
#pragma unroll
    for (int k = 0; k < D; ++k) O[k] = 0.f;
#pragma unroll
    for (int s = 0; s < SPLIT; ++s) {
        float cc = __expf(sm[s][r] - M);
        L = fmaf(cc, sl[s][r], L);
#pragma unroll
        for (int k = 0; k < D; ++k) O[k] = fmaf(cc, so[s][r][k], O[k]);
    }
    return true;
}

// ---- layer-1 attention: direct write (no block-level j split) ----
template<int SPLIT>
__global__ __launch_bounds__(64*SPLIT) void attn1(
        const float* __restrict__ hsrc, const uint32_t* __restrict__ mask,
        const float* __restrict__ bias, float* __restrict__ out) {
    constexpr int JLEN = N / SPLIT;
    const int lane = threadIdx.x & 63;
    const int wv = threadIdx.x >> 6;
    const int row = blockIdx.x * 64 + lane;
    const int head = blockIdx.y;
    const float* __restrict__ hh = hsrc + (size_t)head * N * D;

    float hi[D];
    {
        const float4* r4 = (const float4*)(hh + (size_t)row * D);
#pragma unroll
        for (int k = 0; k < 4; ++k) {
            float4 v = r4[k];
            hi[4*k]=v.x; hi[4*k+1]=v.y; hi[4*k+2]=v.z; hi[4*k+3]=v.w;
        }
    }
    const int j0 = __builtin_amdgcn_readfirstlane(wv * JLEN);
    const uint32_t* __restrict__ mrow = mask + (size_t)row * (N/32) + (j0 >> 5);
    float m = NEG, l = 0.f, o[D] = {};
    attn_slice<SPLIT>(hh, mrow, hi, j0, JLEN, m, l, o);

    float M, L, O[D];
    if (block_merge<SPLIT>(lane, wv, m, l, o, M, L, O)) {
        int t = head >> 3, b = (head >> 2) & 1, hd = head & 3;
        const float* bb = bias + (t * H + hd) * D;
        int rr = blockIdx.x * 64 + threadIdx.x;
        float* orow = out + ((size_t)(t * B + b) * N + rr) * (H * D) + hd * D;
        float inv = 1.0f / L;
#pragma unroll
        for (int k = 0; k < D; ++k) {
            float v = fmaf(O[k], inv, bb[k]);
            orow[k] = (v > 0.f) ? v : 0.01f * v;   // leaky
        }
    }
}

// ---- partial attention: j split across waves AND grid-z blocks ----
template<int SPLIT, int JS>
__global__ __launch_bounds__(64*SPLIT) void attn_p(
        const float* __restrict__ hsrc, const uint32_t* __restrict__ mask,
        float* __restrict__ pm, float* __restrict__ pl, float* __restrict__ po) {
    constexpr int JLEN = N / (SPLIT * JS);
    static_assert(JLEN >= 32, "mask-word floor");
    const int lane = threadIdx.x & 63;
    const int wv = threadIdx.x >> 6;
    const int row = blockIdx.x * 64 + lane;
    const int head = blockIdx.y;
    const int js = blockIdx.z;
    const float* __restrict__ hh = hsrc + (size_t)head * N * D;

    float hi[D];
    {
        const float4* r4 = (const float4*)(hh + (size_t)row * D);
#pragma unroll
        for (int k = 0; k < 4; ++k) {
            float4 v = r4[k];
            hi[4*k]=v.x; hi[4*k+1]=v.y; hi[4*k+2]=v.z; hi[4*k+3]=v.w;
        }
    }
    const int j0 = __builtin_amdgcn_readfirstlane((js * SPLIT + wv) * JLEN);
    const uint32_t* __restrict__ mrow = mask + (size_t)row * (N/32) + (j0 >> 5);
    float m = NEG, l = 0.f, o[D] = {};
    attn_slice<SPLIT>(hh, mrow, hi, j0, JLEN, m, l, o);

    float M, L, O[D];
    if (block_merge<SPLIT>(lane, wv, m, l, o, M, L, O)) {
        int rr = blockIdx.x * 64 + threadIdx.x;
        size_t pidx = ((size_t)head * N + rr) * JS + js;
        pm[pidx] = M;
        pl[pidx] = L;
#pragma unroll
        for (int k = 0; k < D; ++k) po[pidx * D + k] = O[k];
    }
}

// ---- merge JS partials per row, apply bias (+leaky), write per-layer layout --
template<int JS, int LAYER, bool LEAKY>
__global__ void k_merge(const float* __restrict__ pm, const float* __restrict__ pl,
                        const float* __restrict__ po, const float* __restrict__ bias,
                        float* __restrict__ out) {
    int id = blockIdx.x * 256 + threadIdx.x;             // head*N + row
    int row = id & (N - 1);
    int head = id >> 11;
    size_t base = (size_t)id * JS;
    float M = pm[base];
#pragma unroll
    for (int s = 1; s < JS; ++s) M = fmaxf(M, pm[base + s]);
    float L = 0.f, O[D] = {};
#pragma unroll
    for (int s = 0; s < JS; ++s) {
        float cc = __expf(pm[base + s] - M);
        L = fmaf(cc, pl[base + s], L);
        const float* pp = po + (base + s) * D;
#pragma unroll
        for (int k = 0; k < D; ++k) O[k] = fmaf(cc, pp[k], O[k]);
    }
    const float* bb; float* orow;
    if constexpr (LAYER == 2) {
        int t = head >> 1, b = head & 1;
        bb = bias + t * D;
        orow = out + ((size_t)b * N + row) * (T * D) + t * D;   // hidden[b][n][48]
    } else {
        bb = bias;
        orow = out + ((size_t)head * N + row) * D;              // out[b][n][16]
    }
    float inv = 1.0f / L;
#pragma unroll
    for (int k = 0; k < D; ++k) {
        float v = fmaf(O[k], inv, bb[k]);
        if (LEAKY) v = (v > 0.f) ? v : 0.01f * v;
        orow[k] = v;
    }
}

extern "C" void kernel_launch(void* const* d_in, const int* in_sizes, int n_in,
                              void* d_out, int out_size, void* d_ws, size_t ws_size,
                              hipStream_t stream) {
    const float* fx    = (const float*)d_in[0];
    const float* graph = (const float*)d_in[1];
    const float* W1    = (const float*)d_in[2];
    const float* b1    = (const float*)d_in[3];
    const float* W2    = (const float*)d_in[4];
    const float* b2    = (const float*)d_in[5];
    const float* W3    = (const float*)d_in[6];
    const float* b3    = (const float*)d_in[7];
    float* out = (float*)d_out;

    char* ws = (char*)d_ws;
    unsigned long long* mask64 = (unsigned long long*)ws;            // 512 KB
    float* h1     = (float*)(ws + (size_t)(N*(size_t)N/8));          // [24][N][16] 6MB
    float* x2     = h1 + (size_t)T*B*H*N*D;                          // [T][B][N][64] 6MB
    float* h2     = x2 + (size_t)T*B*N*H*D;                          // [T][B][N][16]
    float* hidden = h2 + (size_t)T*B*N*D;                            // [B][N][48]
    float* h3     = hidden + (size_t)B*N*T*D;                        // [B][N][16]

    // partials reuse the h1 region (dead after layer-1 attn):
    constexpr size_t PMAX = (size_t)T*B*N*4;    // layer2: 6 heads * N * JS(4) = 49152
    float* pm = h1;
    float* pl = h1 + PMAX;
    float* po = h1 + 2*PMAX;                    // PMAX*16 floats

    pack_mask<<<N*N/256, 256, 0, stream>>>(graph, mask64);
    k_h1<<<T*B*H*N/256, 256, 0, stream>>>(fx, W1, h1);

    attn1<8><<<dim3(N/64, T*B*H), 512, 0, stream>>>(h1, (const uint32_t*)mask64, b1, x2);
    k_rowmm<H*D,12><<<T*B*N/256, 256, 0, stream>>>(x2, W2, h2);      // t = id>>12

    attn_p<8,4><<<dim3(N/64, T*B, 4), 512, 0, stream>>>(h2, (const uint32_t*)mask64, pm, pl, po);
    k_merge<4,2,true><<<T*B*N/256, 256, 0, stream>>>(pm, pl, po, b2, hidden);

    k_rowmm<T*D,20><<<B*N/256, 256, 0, stream>>>(hidden, W3, h3);    // single W3

    attn_p<8,8><<<dim3(N/64, B, 8), 512, 0, stream>>>(h3, (const uint32_t*)mask64, pm, pl, po);
    k_merge<8,3,false><<<B*N/256, 256, 0, stream>>>(pm, pl, po, b3, out);
}

// Round 3
// 292.430 us; speedup vs baseline: 1.5895x; 1.0497x over previous
//
#include <hip/hip_runtime.h>
#include <stdint.h>

static constexpr int N = 2048;
static constexpr int B = 2;
static constexpr int T = 3;
static constexpr int H = 4;
static constexpr int D = 16;
static constexpr float NEG = -1e30f;
static constexpr float LOG2E = 1.4426950408889634f;

typedef float v2f __attribute__((ext_vector_type(2)));
typedef float v4f __attribute__((ext_vector_type(4)));

__device__ __forceinline__ v2f pk_fma(v2f a, v2f b, v2f c) {
    return __builtin_elementwise_fma(a, b, c);
}

// ---- pack graph!=0 into bits: mask64[i*32 + j/64] ----
__global__ void pack_mask(const float* __restrict__ g, unsigned long long* __restrict__ mb) {
    int idx = blockIdx.x * 256 + threadIdx.x;            // over N*N
    float v = g[idx];
    unsigned long long bal = __ballot(v != 0.0f);
    if ((threadIdx.x & 63) == 0) mb[idx >> 6] = bal;
}

// ---- h1[t][b][h][n][d] = sum_c flow_x[b][n][t][c] * W1[t][h][c][d] ----
__global__ void k_h1(const float* __restrict__ fx, const float* __restrict__ W1,
                     float* __restrict__ h1) {
    int id = blockIdx.x * 256 + threadIdx.x;             // T*B*H*N threads
    int n = id & (N - 1);
    int head = id >> 11;                                 // (t*B+b)*H+h
    int t = head >> 3;
    int b = (head >> 2) & 1;
    int h = head & 3;
    const float* f = fx + (((size_t)(b * N + n)) * T + t) * D;
    const float* w = W1 + ((t * H + h) * D) * (size_t)D;
    float fr[D];
    const float4* f4 = (const float4*)f;
#pragma unroll
    for (int k = 0; k < 4; ++k) {
        float4 v = f4[k];
        fr[4*k] = v.x; fr[4*k+1] = v.y; fr[4*k+2] = v.z; fr[4*k+3] = v.w;
    }
    float acc[D] = {};
#pragma unroll
    for (int c = 0; c < D; ++c)
#pragma unroll
        for (int d = 0; d < D; ++d) acc[d] = fmaf(fr[c], w[c*D+d], acc[d]);
    float* o = h1 + (size_t)id * D;
#pragma unroll
    for (int d = 0; d < D; ++d) o[d] = acc[d];
}

// ---- y[r][q*4..q*4+3] = x[r][:] @ W[(r>>SHIFT)][:][q*4..+3]; 4 outs/thread ----
template<int KIN, int SHIFT>
__global__ void k_rowmm(const float* __restrict__ x, const float* __restrict__ Wbase,
                        float* __restrict__ y) {
    int id = blockIdx.x * 256 + threadIdx.x;             // rows*4
    int r = id >> 2, q = id & 3;
    const float* __restrict__ xr = x + (size_t)r * KIN;
    const float* __restrict__ w = Wbase + (size_t)(r >> SHIFT) * KIN * D + q * 4;
    float acc[4] = {};
    const float4* x4 = (const float4*)xr;
#pragma unroll
    for (int c4 = 0; c4 < KIN/4; ++c4) {
        float4 xv = x4[c4];
        float xs[4] = {xv.x, xv.y, xv.z, xv.w};
#pragma unroll
        for (int p = 0; p < 4; ++p) {
            int c = c4*4 + p;
#pragma unroll
            for (int d = 0; d < 4; ++d) acc[d] = fmaf(xs[p], w[c*D+d], acc[d]);
        }
    }
    float* o = y + (size_t)r * D + q * 4;
#pragma unroll
    for (int d = 0; d < 4; ++d) o[d] = acc[d];
}

// ================= shared inner loop (online softmax over a j-slice) =========
// hi is pre-scaled by LOG2E; m,l are in exp2 domain. o/l ratio is exact.
__device__ __forceinline__ void attn_slice(
        const float* __restrict__ hh, const uint32_t* __restrict__ mrow,
        const v2f (&hi)[8], int j0, int jlen,
        float& m, float& l, v2f (&o)[8]) {
    for (int w = 0; w < jlen/32; ++w) {
        uint32_t mw = mrow[w];
        const float* __restrict__ tb = hh + (size_t)(j0 + w*32) * D;
#pragma unroll 4
        for (int u = 0; u < 32; ++u) {
            const v4f* h4 = (const v4f*)(tb + u*D);
            v4f A = h4[0], Bv = h4[1], C = h4[2], Dv = h4[3];
            v2f a0 = {0.f, 0.f}, a1 = {0.f, 0.f};
            a0 = pk_fma(hi[0], A.lo,  a0); a1 = pk_fma(hi[1], A.hi,  a1);
            a0 = pk_fma(hi[2], Bv.lo, a0); a1 = pk_fma(hi[3], Bv.hi, a1);
            a0 = pk_fma(hi[4], C.lo,  a0); a1 = pk_fma(hi[5], C.hi,  a1);
            a0 = pk_fma(hi[6], Dv.lo, a0); a1 = pk_fma(hi[7], Dv.hi, a1);
            float s = (a0.x + a0.y) + (a1.x + a1.y);
            float se = (mw & (1u << u)) ? s : NEG;
            if (se > m) {                      // wave-rare after warmup
                float cc = __builtin_amdgcn_exp2f(m - se);
                l *= cc;
                v2f c2 = {cc, cc};
#pragma unroll
                for (int p = 0; p < 8; ++p) o[p] *= c2;
                m = se;
            }
            float wg = __builtin_amdgcn_exp2f(se - m);
            l += wg;
            v2f w2 = {wg, wg};
            o[0] = pk_fma(w2, A.lo,  o[0]);
            o[1] = pk_fma(w2, A.hi,  o[1]);
            o[2] = pk_fma(w2, Bv.lo, o[2]);
            o[3] = pk_fma(w2, Bv.hi, o[3]);
            o[4] = pk_fma(w2, C.lo,  o[4]);
            o[5] = pk_fma(w2, C.hi,  o[5]);
            o[6] = pk_fma(w2, Dv.lo, o[6]);
            o[7] = pk_fma(w2, Dv.hi, o[7]);
        }
    }
}

// load hi row, pre-scaled by LOG2E
__device__ __forceinline__ void load_hi(const float* __restrict__ hh, int row, v2f (&hi)[8]) {
    const v4f* r4 = (const v4f*)(hh + (size_t)row * D);
#pragma unroll
    for (int k = 0; k < 4; ++k) {
        v4f v = r4[k];
        hi[2*k]   = v.lo * LOG2E;
        hi[2*k+1] = v.hi * LOG2E;
    }
}

// LDS merge of SPLIT wave-partials -> lane r (threadIdx.x<64) returns (M,L,O)
template<int SPLIT>
__device__ __forceinline__ bool block_merge(
        int lane, int wv, float m, float l, const v2f (&o)[8],
        float& M, float& L, float (&O)[D]) {
    __shared__ float sm[SPLIT][64];
    __shared__ float sl[SPLIT][64];
    __shared__ float so[SPLIT][64][D+1];
    sm[wv][lane] = m;
    sl[wv][lane] = l;
#pragma unroll
    for (int k = 0; k < 8; ++k) {
        so[wv][lane][2*k]   = o[k].x;
        so[wv][lane][2*k+1] = o[k].y;
    }
    __syncthreads();
    if (threadIdx.x >= 64) return false;
    int r = threadIdx.x;
    M = sm[0][r];
#pragma unroll
    for (int s = 1; s < SPLIT; ++s) M = fmaxf(M, sm[s][r]);
    L = 0.f;
#pragma unroll
    for (int k = 0; k < D; ++k) O[k] = 0.f;
#pragma unroll
    for (int s = 0; s < SPLIT; ++s) {
        float cc = __builtin_amdgcn_exp2f(sm[s][r] - M);
        L = fmaf(cc, sl[s][r], L);
#pragma unroll
        for (int k = 0; k < D; ++k) O[k] = fmaf(cc, so[s][r][k], O[k]);
    }
    return true;
}

// ---- layer-1 attention: direct write ----
template<int SPLIT>
__global__ __launch_bounds__(64*SPLIT) void attn1(
        const float* __restrict__ hsrc, const uint32_t* __restrict__ mask,
        const float* __restrict__ bias, float* __restrict__ out) {
    constexpr int JLEN = N / SPLIT;
    const int lane = threadIdx.x & 63;
    const int wv = threadIdx.x >> 6;
    const int row = blockIdx.x * 64 + lane;
    const int head = blockIdx.y;
    const float* __restrict__ hh = hsrc + (size_t)head * N * D;

    v2f hi[8];
    load_hi(hh, row, hi);
    const int j0 = __builtin_amdgcn_readfirstlane(wv * JLEN);
    const uint32_t* __restrict__ mrow = mask + (size_t)row * (N/32) + (j0 >> 5);
    float m = NEG, l = 0.f;
    v2f o[8];
#pragma unroll
    for (int p = 0; p < 8; ++p) o[p] = (v2f){0.f, 0.f};
    attn_slice(hh, mrow, hi, j0, JLEN, m, l, o);

    float M, L, O[D];
    if (block_merge<SPLIT>(lane, wv, m, l, o, M, L, O)) {
        int t = head >> 3, b = (head >> 2) & 1, hd = head & 3;
        const float* bb = bias + (t * H + hd) * D;
        int rr = blockIdx.x * 64 + threadIdx.x;
        float* orow = out + ((size_t)(t * B + b) * N + rr) * (H * D) + hd * D;
        float inv = 1.0f / L;
#pragma unroll
        for (int k = 0; k < D; ++k) {
            float v = fmaf(O[k], inv, bb[k]);
            orow[k] = (v > 0.f) ? v : 0.01f * v;   // leaky
        }
    }
}

// ---- partial attention: j split across waves AND grid-z blocks ----
template<int SPLIT, int JS>
__global__ __launch_bounds__(64*SPLIT) void attn_p(
        const float* __restrict__ hsrc, const uint32_t* __restrict__ mask,
        float* __restrict__ pm, float* __restrict__ pl, float* __restrict__ po) {
    constexpr int JLEN = N / (SPLIT * JS);
    static_assert(JLEN >= 32, "mask-word floor");
    const int lane = threadIdx.x & 63;
    const int wv = threadIdx.x >> 6;
    const int row = blockIdx.x * 64 + lane;
    const int head = blockIdx.y;
    const int js = blockIdx.z;
    const float* __restrict__ hh = hsrc + (size_t)head * N * D;

    v2f hi[8];
    load_hi(hh, row, hi);
    const int j0 = __builtin_amdgcn_readfirstlane((js * SPLIT + wv) * JLEN);
    const uint32_t* __restrict__ mrow = mask + (size_t)row * (N/32) + (j0 >> 5);
    float m = NEG, l = 0.f;
    v2f o[8];
#pragma unroll
    for (int p = 0; p < 8; ++p) o[p] = (v2f){0.f, 0.f};
    attn_slice(hh, mrow, hi, j0, JLEN, m, l, o);

    float M, L, O[D];
    if (block_merge<SPLIT>(lane, wv, m, l, o, M, L, O)) {
        int rr = blockIdx.x * 64 + threadIdx.x;
        size_t pidx = ((size_t)head * N + rr) * JS + js;
        pm[pidx] = M;
        pl[pidx] = L;
#pragma unroll
        for (int k = 0; k < D; ++k) po[pidx * D + k] = O[k];
    }
}

// ---- merge JS partials per row, apply bias (+leaky), write per-layer layout --
template<int JS, int LAYER, bool LEAKY>
__global__ void k_merge(const float* __restrict__ pm, const float* __restrict__ pl,
                        const float* __restrict__ po, const float* __restrict__ bias,
                        float* __restrict__ out) {
    int id = blockIdx.x * 256 + threadIdx.x;             // head*N + row
    int row = id & (N - 1);
    int head = id >> 11;
    size_t base = (size_t)id * JS;
    float M = pm[base];
#pragma unroll
    for (int s = 1; s < JS; ++s) M = fmaxf(M, pm[base + s]);
    float L = 0.f, O[D] = {};
#pragma unroll
    for (int s = 0; s < JS; ++s) {
        float cc = __builtin_amdgcn_exp2f(pm[base + s] - M);
        L = fmaf(cc, pl[base + s], L);
        const float* pp = po + (base + s) * D;
#pragma unroll
        for (int k = 0; k < D; ++k) O[k] = fmaf(cc, pp[k], O[k]);
    }
    const float* bb; float* orow;
    if constexpr (LAYER == 2) {
        int t = head >> 1, b = head & 1;
        bb = bias + t * D;
        orow = out + ((size_t)b * N + row) * (T * D) + t * D;   // hidden[b][n][48]
    } else {
        bb = bias;
        orow = out + ((size_t)head * N + row) * D;              // out[b][n][16]
    }
    float inv = 1.0f / L;
#pragma unroll
    for (int k = 0; k < D; ++k) {
        float v = fmaf(O[k], inv, bb[k]);
        if (LEAKY) v = (v > 0.f) ? v : 0.01f * v;
        orow[k] = v;
    }
}

extern "C" void kernel_launch(void* const* d_in, const int* in_sizes, int n_in,
                              void* d_out, int out_size, void* d_ws, size_t ws_size,
                              hipStream_t stream) {
    const float* fx    = (const float*)d_in[0];
    const float* graph = (const float*)d_in[1];
    const float* W1    = (const float*)d_in[2];
    const float* b1    = (const float*)d_in[3];
    const float* W2    = (const float*)d_in[4];
    const float* b2    = (const float*)d_in[5];
    const float* W3    = (const float*)d_in[6];
    const float* b3    = (const float*)d_in[7];
    float* out = (float*)d_out;

    char* ws = (char*)d_ws;
    unsigned long long* mask64 = (unsigned long long*)ws;            // 512 KB
    float* h1     = (float*)(ws + (size_t)(N*(size_t)N/8));          // [24][N][16] 6MB
    float* x2     = h1 + (size_t)T*B*H*N*D;                          // [T][B][N][64] 6MB
    float* h2     = x2 + (size_t)T*B*N*H*D;                          // [T][B][N][16]
    float* hidden = h2 + (size_t)T*B*N*D;                            // [B][N][48]
    float* h3     = hidden + (size_t)B*N*T*D;                        // [B][N][16]

    // partials reuse the h1 region (dead after layer-1 attn):
    constexpr size_t PMAX = (size_t)T*B*N*4;    // layer2: 6 heads * N * JS(4)
    float* pm = h1;
    float* pl = h1 + PMAX;
    float* po = h1 + 2*PMAX;                    // PMAX*16 floats

    pack_mask<<<N*N/256, 256, 0, stream>>>(graph, mask64);
    k_h1<<<T*B*H*N/256, 256, 0, stream>>>(fx, W1, h1);

    attn1<8><<<dim3(N/64, T*B*H), 512, 0, stream>>>(h1, (const uint32_t*)mask64, b1, x2);
    k_rowmm<H*D,12><<<T*B*N*4/256, 256, 0, stream>>>(x2, W2, h2);    // t = r>>12

    attn_p<8,4><<<dim3(N/64, T*B, 4), 512, 0, stream>>>(h2, (const uint32_t*)mask64, pm, pl, po);
    k_merge<4,2,true><<<T*B*N/256, 256, 0, stream>>>(pm, pl, po, b2, hidden);

    k_rowmm<T*D,20><<<B*N*4/256, 256, 0, stream>>>(hidden, W3, h3);  // single W3

    attn_p<8,8><<<dim3(N/64, B, 8), 512, 0, stream>>>(h3, (const uint32_t*)mask64, pm, pl, po);
    k_merge<8,3,false><<<B*N/256, 256, 0, stream>>>(pm, pl, po, b3, out);
}